// Round 2
// baseline (62102.277 us; speedup 1.0000x reference)
//
#include <hip/hip_runtime.h>
#include <cstdint>
#include <cstddef>
#include <cstdio>

// ---------------------------------------------------------------------------
// IntentClassifier on MI355X.
//   dense(1024->1024) folded into layer0 Wi (Wc = W_reg@Wi0)
//   2x BiLSTM (H=768): persistent grid-barrier kernel, x@Wi fused via LDS-
//     resident Wi slice (1-pass bf16), h@Wh via register-pinned split-bf16
//     (3-pass). 192 wgs, LDS >80KB => 1 block/CU => co-residency structural.
//   attention: split-bf16 GEMM with fused tanh+energy reduction, softmax,
//     context, 2 small dense layers.
// ws footprint ~267 MB (round-0's 687 MB suspected of overflowing d_ws).
// ---------------------------------------------------------------------------

typedef __attribute__((ext_vector_type(8))) short s8v;   // 8 x bf16
typedef __attribute__((ext_vector_type(4))) short s4v;
typedef __attribute__((ext_vector_type(4))) float f4v;

#define MFMA16(a,b,c) __builtin_amdgcn_mfma_f32_16x16x32_bf16((a),(b),(c),0,0,0)

#define NB   64
#define NT   512
#define MTOT (NB*NT)     // 32768 rows

__device__ __forceinline__ ushort f2bf(float x){
  uint32_t u = __float_as_uint(x);
  uint32_t r = (u + 0x7FFFu + ((u >> 16) & 1u)) >> 16;   // RNE
  return (ushort)r;
}
__device__ __forceinline__ float bf2f(ushort h){
  return __uint_as_float(((uint32_t)h) << 16);
}
__device__ __forceinline__ float fsig(float x){
  x = fminf(30.f, fmaxf(-30.f, x));
  return 1.f / (1.f + __expf(-x));
}
__device__ __forceinline__ float ftanh(float x){
  x = fminf(15.f, fmaxf(-15.f, x));
  float e = __expf(2.f * x);
  return (e - 1.f) / (e + 1.f);
}

// ------------------------- weight prep kernels -----------------------------
// B (K,N) fp32 -> B^T (N,K) bf16 hi/lo (k-contiguous rows for MFMA B-frags)
__global__ void transpose_split_kernel(const float* __restrict__ B,
                                       ushort* __restrict__ Th,
                                       ushort* __restrict__ Tl,
                                       int K, int N){
  __shared__ float tile[64][65];
  int k0 = blockIdx.x * 64, n0 = blockIdx.y * 64;
  for (int i = threadIdx.x; i < 4096; i += 256){
    int r = i >> 6, c = i & 63;
    tile[r][c] = B[(size_t)(k0 + r) * N + (n0 + c)];
  }
  __syncthreads();
  for (int i = threadIdx.x; i < 4096; i += 256){
    int nr = i >> 6, kc = i & 63;
    float x = tile[kc][nr];
    ushort h = f2bf(x);
    ushort lo = f2bf(x - bf2f(h));
    size_t o = (size_t)(n0 + nr) * K + (k0 + kc);
    Th[o] = h; Tl[o] = lo;
  }
}

// Wh (768,3072) fp32 -> fragment-packed bf16 hi/lo: [wgd(96)][nt(2)][kt(24)][lane(64)][j(8)]
__global__ void whpack_kernel(const float* __restrict__ Wh,
                              ushort* __restrict__ Ph, ushort* __restrict__ Pl){
  int idx = blockIdx.x * 256 + threadIdx.x;     // 2,359,296 total
  int j    = idx & 7;
  int lane = (idx >> 3) & 63;
  int kt   = (idx >> 9) % 24;
  int rest = idx / (24 * 512);                  // wgd*2 + nt
  int nt   = rest & 1;
  int wgd  = rest >> 1;
  int c    = lane & 15;
  int gate = nt * 2 + (c >> 3);
  int q    = wgd * 8 + (c & 7);
  int k    = kt * 32 + (lane >> 4) * 8 + j;
  float x = Wh[(size_t)k * 3072 + gate * 768 + q];
  ushort h = f2bf(x);
  Ph[idx] = h;
  Pl[idx] = f2bf(x - bf2f(h));
}

// W (K,3072) fp32 -> packed bf16 [wgd(96)][n(32)][k(K)], col(n)=(n>>3)*768+wgd*8+(n&7)
__global__ void pack_wi_kernel(const float* __restrict__ W,
                               ushort* __restrict__ dst, int K){
  int total = 96 * 32 * K;
  for (int idx = blockIdx.x * 256 + threadIdx.x; idx < total; idx += gridDim.x * 256){
    int k = idx % K;
    int rest = idx / K;            // wgd*32 + n
    int n = rest & 31, wgd = rest >> 5;
    float x = W[(size_t)k * 3072 + (n >> 3) * 768 + wgd * 8 + (n & 7)];
    dst[idx] = f2bf(x);
  }
}

// bc[d][c] = b_d[c] + sum_k breg[k]*W_d[k,c]   (W=nullptr -> plain copy)
__global__ void bias_comb_kernel(const float* __restrict__ bf, const float* __restrict__ bb,
                                 const float* __restrict__ Wf, const float* __restrict__ Wb,
                                 const float* __restrict__ breg, int Kb,
                                 float* __restrict__ bc){
  int c = blockIdx.x * 256 + threadIdx.x;   // < 3072
  int d = blockIdx.y;
  const float* b = d ? bb : bf;
  const float* W = d ? Wb : Wf;
  float acc = b[c];
  if (W){
    for (int k = 0; k < Kb; k++) acc += breg[k] * W[(size_t)k * 3072 + c];
  }
  bc[d * 3072 + c] = acc;
}

__global__ void zero_kernel(uint32_t* __restrict__ p, int n){
  for (int i = blockIdx.x * 256 + threadIdx.x; i < n; i += gridDim.x * 256)
    p[i] = 0u;
}

// ------------------------- split-bf16 GEMM ---------------------------------
// MODE 0: C = A@B + bias (fp32 out).   MODE 2: scores[row] += sum_col tanh(C)*We[col]
// ABF 0: A fp32 (split in-kernel, 3-pass).  ABF 1: A bf16 (2-pass: ah*bh + ah*bl)
template<int MODE, int ABF>
__global__ __launch_bounds__(256, 2) void gemm_kernel(
    const void* __restrict__ Araw, const ushort* __restrict__ Bh,
    const ushort* __restrict__ Bl, const float* __restrict__ bias,
    float* __restrict__ outF,
    const float* __restrict__ We, float* __restrict__ scores,
    int M, int N, int K)
{
  __shared__ short lA_h[128*40], lA_l[128*40], lB_h[128*40], lB_l[128*40];
  int tid = threadIdx.x, l = tid & 63, w = tid >> 6;
  int wr = w >> 1, wc = w & 1;
  int nbM = M >> 7;
  int mblk = blockIdx.x % nbM, nblk = blockIdx.x / nbM;
  f4v acc[4][4];
  for (int i=0;i<4;i++) for (int j=0;j<4;j++) acc[i][j] = (f4v){0.f,0.f,0.f,0.f};
  int nk = K >> 5;
  const ushort* Bhb = Bh + (size_t)nblk*128*K;
  const ushort* Blb = Bl + (size_t)nblk*128*K;
  int mrow = l & 15, koff = (l >> 4) * 8;
  for (int kt = 0; kt < nk; kt++){
    if (ABF == 0){   // fp32 A -> split hi/lo
      const float* Ab = (const float*)Araw + (size_t)mblk*128*K;
      int c4 = (l & 7) * 4;
      #pragma unroll
      for (int i=0;i<4;i++){
        int r = (w*4 + i)*8 + (l >> 3);
        const float* p = Ab + (size_t)r*K + kt*32 + c4;
        float4 v = *(const float4*)p;
        float xs[4] = {v.x, v.y, v.z, v.w};
        s4v hv, lv;
        #pragma unroll
        for (int j=0;j<4;j++){
          ushort hh = f2bf(xs[j]);
          hv[j] = (short)hh;
          lv[j] = (short)f2bf(xs[j] - bf2f(hh));
        }
        *(s4v*)&lA_h[r*40 + c4] = hv;
        *(s4v*)&lA_l[r*40 + c4] = lv;
      }
    } else {         // bf16 A
      const ushort* Ab = (const ushort*)Araw + (size_t)mblk*128*K;
      int k8 = (l & 3) * 8;
      #pragma unroll
      for (int i=0;i<2;i++){
        int r = (w*2 + i)*16 + (l >> 2);
        *(s8v*)&lA_h[r*40 + k8] = *(const s8v*)(Ab + (size_t)r*K + kt*32 + k8);
      }
    }
    {
      int k8 = (l & 3) * 8;
      #pragma unroll
      for (int i=0;i<2;i++){
        int r = (w*2 + i)*16 + (l >> 2);
        size_t o = (size_t)r*K + kt*32 + k8;
        *(s8v*)&lB_h[r*40 + k8] = *(const s8v*)(Bhb + o);
        *(s8v*)&lB_l[r*40 + k8] = *(const s8v*)(Blb + o);
      }
    }
    __syncthreads();
    s8v ah[4], al[4], bh[4], bl[4];
    #pragma unroll
    for (int mt=0;mt<4;mt++){
      int base = (wr*64 + mt*16 + mrow)*40 + koff;
      ah[mt] = *(s8v*)&lA_h[base];
      if (ABF == 0) al[mt] = *(s8v*)&lA_l[base];
    }
    #pragma unroll
    for (int nt=0;nt<4;nt++){
      int base = (wc*64 + nt*16 + mrow)*40 + koff;
      bh[nt] = *(s8v*)&lB_h[base];
      bl[nt] = *(s8v*)&lB_l[base];
    }
    #pragma unroll
    for (int mt=0;mt<4;mt++)
      #pragma unroll
      for (int nt=0;nt<4;nt++){
        acc[mt][nt] = MFMA16(ah[mt], bh[nt], acc[mt][nt]);
        acc[mt][nt] = MFMA16(ah[mt], bl[nt], acc[mt][nt]);
        if (ABF == 0) acc[mt][nt] = MFMA16(al[mt], bh[nt], acc[mt][nt]);
      }
    __syncthreads();
  }
  // epilogue. C/D layout: col = lane&15, row = (lane>>4)*4 + r
  if (MODE == 2){
    float pre[4][4];
    #pragma unroll
    for (int mt=0;mt<4;mt++) for (int r=0;r<4;r++) pre[mt][r] = 0.f;
    #pragma unroll
    for (int nt=0;nt<4;nt++){
      int colg = nblk*128 + wc*64 + nt*16 + (l & 15);
      float we = We[colg];
      #pragma unroll
      for (int mt=0;mt<4;mt++)
        #pragma unroll
        for (int r=0;r<4;r++)
          pre[mt][r] += ftanh(acc[mt][nt][r]) * we;
    }
    #pragma unroll
    for (int mt=0;mt<4;mt++)
      #pragma unroll
      for (int r=0;r<4;r++){
        float v = pre[mt][r];
        v += __shfl_xor(v, 1); v += __shfl_xor(v, 2);
        v += __shfl_xor(v, 4); v += __shfl_xor(v, 8);
        if ((l & 15) == 0){
          int rowg = mblk*128 + wr*64 + mt*16 + (l>>4)*4 + r;
          atomicAdd(scores + rowg, v);
        }
      }
  } else {
    #pragma unroll
    for (int mt=0;mt<4;mt++)
      #pragma unroll
      for (int nt=0;nt<4;nt++){
        int rowg0 = mblk*128 + wr*64 + mt*16 + (l>>4)*4;
        int colg  = nblk*128 + wc*64 + nt*16 + (l & 15);
        float bv = bias ? bias[colg] : 0.f;
        #pragma unroll
        for (int r=0;r<4;r++){
          float v = acc[mt][nt][r] + bv;
          outF[(size_t)(rowg0 + r)*N + colg] = v;
        }
      }
  }
}

// ------------------------- fused persistent BiLSTM -------------------------
// grid = 192 x 256. dir = bx&1, wgd = bx>>1 owns 8 h-cols (32 z-cols).
// Per step: z = x_t@Wi (LDS Wi, 1-pass bf16, prefetched behind barrier)
//            + h@Wh (register-pinned split, 3-pass) + bias; gates; h/c/enc.
// LDS > 80KB => exactly 1 block/CU => all 192 wgs co-resident (barrier safe).
template<int NKT, int XF32>
__global__ __launch_bounds__(256, 1) void recur_fused(
    const void* __restrict__ xsrc, const ushort* __restrict__ wip,
    const ushort* __restrict__ whfh, const ushort* __restrict__ whfl,
    const ushort* __restrict__ whbh, const ushort* __restrict__ whbl,
    const float* __restrict__ bias2, ushort* __restrict__ enc,
    const int* __restrict__ nf, ushort* __restrict__ hstate,
    float* __restrict__ cstate, int* __restrict__ barr)
{
  constexpr int K  = NKT * 32;
  constexpr int KP = K + 8;           // +8 bf16 pad: 2-way (free) LDS conflicts
  constexpr int KPW = NKT / 4;
  __shared__ ushort wilds[32 * KP];
  __shared__ float zlds[9216];        // [w][mt][nt][col16][row pad18]
  __shared__ float bcs[32];
  __shared__ int nfs[64];
  __shared__ int lmaxs[4];
  const int tid = threadIdx.x, l = tid & 63, w = tid >> 6;
  const int dir = blockIdx.x & 1, wgd = blockIdx.x >> 1, wq0 = wgd * 8;

  { // stage this wg's Wi slice into LDS
    const ushort* wsrc = wip + ((size_t)(dir*96 + wgd)) * 32 * K;
    for (int idx = tid; idx < 32 * (K/8); idx += 256){
      int row = idx / (K/8);
      int c8  = (idx - row * (K/8)) * 8;
      *(s8v*)&wilds[row*KP + c8] = *(const s8v*)(wsrc + (size_t)row*K + c8);
    }
  }
  if (tid < 64) nfs[tid] = nf[tid];
  if (tid < 32) bcs[tid] = bias2[dir*3072 + (tid>>3)*768 + wq0 + (tid&7)];
  __syncthreads();
  if (tid < 4){
    int m = 0;
    for (int i=0;i<16;i++) m = max(m, nfs[tid*16 + i]);
    lmaxs[tid] = m;
  }
  __syncthreads();
  int lm[4], Lbl[4];
  #pragma unroll
  for (int mt=0;mt<4;mt++){ lm[mt] = lmaxs[mt]; Lbl[mt] = nfs[mt*16 + (l&15)]; }
  int cb[2], cq[2], cL[2], chid[2];
  #pragma unroll
  for (int cc=0;cc<2;cc++){
    int cell = tid + cc*256;
    cb[cc] = cell >> 3; cq[cc] = cell & 7;
    cL[cc] = nfs[cb[cc]]; chid[cc] = cb[cc]*768 + wq0 + cq[cc];
  }
  float* cst = cstate + dir * 49152;

  const ushort* wph = dir ? whbh : whfh;
  const ushort* wpl = dir ? whbl : whfl;
  s8v whh[2][6], whl[2][6];
  #pragma unroll
  for (int nt=0;nt<2;nt++)
    for (int i=0;i<6;i++){
      size_t o = ((size_t)((wgd*2 + nt)*24 + (w*6 + i)) * 64 + l) * 8;
      whh[nt][i] = *(const s8v*)(wph + o);
      whl[nt][i] = *(const s8v*)(wpl + o);
    }

  f4v aX[4][2];
  auto xpart = [&](int t){
    #pragma unroll
    for (int mt=0;mt<4;mt++){ aX[mt][0]=(f4v){0.f,0.f,0.f,0.f}; aX[mt][1]=(f4v){0.f,0.f,0.f,0.f}; }
    #pragma unroll
    for (int i=0;i<KPW;i++){
      int kt = w*KPW + i;
      int kc = kt*32 + (l>>4)*8;
      s8v bf0 = *(const s8v*)&wilds[(l & 15)*KP + kc];
      s8v bf1 = *(const s8v*)&wilds[(16 + (l & 15))*KP + kc];
      #pragma unroll
      for (int mt=0;mt<4;mt++){
        if (t >= lm[mt]) continue;
        int bb = mt*16 + (l & 15);
        int r = t;
        if (dir && t < Lbl[mt]) r = Lbl[mt] - 1 - t;
        size_t off = ((size_t)bb*512 + r)*K + kc;
        s8v a;
        if constexpr (XF32){
          const float* xf = (const float*)xsrc;
          float4 u0 = *(const float4*)(xf + off);
          float4 u1 = *(const float4*)(xf + off + 4);
          a[0]=(short)f2bf(u0.x); a[1]=(short)f2bf(u0.y);
          a[2]=(short)f2bf(u0.z); a[3]=(short)f2bf(u0.w);
          a[4]=(short)f2bf(u1.x); a[5]=(short)f2bf(u1.y);
          a[6]=(short)f2bf(u1.z); a[7]=(short)f2bf(u1.w);
        } else {
          a = *(const s8v*)((const ushort*)xsrc + off);
        }
        aX[mt][0] = MFMA16(a, bf0, aX[mt][0]);
        aX[mt][1] = MFMA16(a, bf1, aX[mt][1]);
      }
    }
  };
  xpart(0);
  const int g8 = blockIdx.x & 7;

  for (int t = 0; t < 512; t++){
    if (t > 0 && tid == 0){
      while (__hip_atomic_load(barr + 144, __ATOMIC_ACQUIRE, __HIP_MEMORY_SCOPE_AGENT) < t)
        __builtin_amdgcn_s_sleep(2);
    }
    __syncthreads();
    __threadfence();   // invalidate L1 before reading other wgs' h
    const int p = t & 1;
    const ushort* hr_hi = hstate + ((size_t)((dir*2 + p)*2 + 0)) * 49152;
    const ushort* hr_lo = hstate + ((size_t)((dir*2 + p)*2 + 1)) * 49152;
    ushort* hw_hi = hstate + ((size_t)((dir*2 + (p^1))*2 + 0)) * 49152;
    ushort* hw_lo = hstate + ((size_t)((dir*2 + (p^1))*2 + 1)) * 49152;

    f4v acc[4][2];
    #pragma unroll
    for (int mt=0;mt<4;mt++){ acc[mt][0] = aX[mt][0]; acc[mt][1] = aX[mt][1]; }

    #pragma unroll
    for (int i=0;i<6;i++){
      int kc = (w*6 + i)*32 + (l>>4)*8;
      #pragma unroll
      for (int mt=0;mt<4;mt++){
        if (t >= lm[mt]) continue;
        size_t o = (size_t)(mt*16 + (l & 15))*768 + kc;
        s8v ahh = *(const s8v*)(hr_hi + o);
        s8v ahl = *(const s8v*)(hr_lo + o);
        acc[mt][0] = MFMA16(ahh, whh[0][i], acc[mt][0]);
        acc[mt][0] = MFMA16(ahh, whl[0][i], acc[mt][0]);
        acc[mt][0] = MFMA16(ahl, whh[0][i], acc[mt][0]);
        acc[mt][1] = MFMA16(ahh, whh[1][i], acc[mt][1]);
        acc[mt][1] = MFMA16(ahh, whl[1][i], acc[mt][1]);
        acc[mt][1] = MFMA16(ahl, whh[1][i], acc[mt][1]);
      }
    }
    #pragma unroll
    for (int mt=0;mt<4;mt++)
      #pragma unroll
      for (int nt=0;nt<2;nt++){
        int base = (((w*4 + mt)*2 + nt)*16 + (l & 15))*18 + (l>>4)*4;
        zlds[base+0] = acc[mt][nt][0];
        zlds[base+1] = acc[mt][nt][1];
        zlds[base+2] = acc[mt][nt][2];
        zlds[base+3] = acc[mt][nt][3];
      }
    __syncthreads();
    #pragma unroll
    for (int cc=0; cc<2; cc++){
      int b = cb[cc], q = cq[cc], Lb = cL[cc], hidx = chid[cc];
      if (t < Lb){
        int mt = b >> 4, row = b & 15;
        float zg4[4];
        #pragma unroll
        for (int g=0; g<4; g++){
          int nt = g >> 1, c = (g & 1)*8 + q;
          int zb = ((mt*2 + nt)*16 + c)*18 + row;
          zg4[g] = zlds[zb] + zlds[zb+2304] + zlds[zb+4608] + zlds[zb+6912] + bcs[g*8 + q];
        }
        float co = cst[hidx];
        float nc = fsig(zg4[1])*co + fsig(zg4[0])*ftanh(zg4[2]);
        float nh = fsig(zg4[3])*ftanh(nc);
        cst[hidx] = nc;
        ushort hh = f2bf(nh);
        hw_hi[hidx] = hh;
        hw_lo[hidx] = f2bf(nh - bf2f(hh));
        int r = dir ? (Lb - 1 - t) : t;
        enc[((size_t)b*512 + r)*1536 + dir*768 + wq0 + q] = f2bf(nh);
      } else {
        hw_hi[hidx] = hr_hi[hidx];
        hw_lo[hidx] = hr_lo[hidx];
      }
    }
    __threadfence();
    __syncthreads();
    if (tid == 0){   // 2-level arrival tree: 8 groups of 24, then 8 -> gen
      int prev = __hip_atomic_fetch_add(barr + g8*16, 1, __ATOMIC_ACQ_REL, __HIP_MEMORY_SCOPE_AGENT);
      if (prev == 23){
        __hip_atomic_store(barr + g8*16, 0, __ATOMIC_RELAXED, __HIP_MEMORY_SCOPE_AGENT);
        int p2 = __hip_atomic_fetch_add(barr + 128, 1, __ATOMIC_ACQ_REL, __HIP_MEMORY_SCOPE_AGENT);
        if (p2 == 7){
          __hip_atomic_store(barr + 128, 0, __ATOMIC_RELAXED, __HIP_MEMORY_SCOPE_AGENT);
          __hip_atomic_store(barr + 144, t + 1, __ATOMIC_RELEASE, __HIP_MEMORY_SCOPE_AGENT);
        }
      }
    }
    if (t < 511) xpart(t + 1);   // prefetch next x@Wi behind others' arrival
  }
}

// ------------------------- attention tail ----------------------------------
__global__ void softmax_kernel(const float* __restrict__ scores,
                               const int* __restrict__ nf,
                               float* __restrict__ attn){
  __shared__ float red[4], red2[4];
  int b = blockIdx.x, tid = threadIdx.x;
  int L = nf[b];
  float v0 = (tid       < L) ? scores[b*512 + tid]       : -1e30f;
  float v1 = (tid + 256 < L) ? scores[b*512 + tid + 256] : -1e30f;
  float mx = fmaxf(v0, v1);
  for (int m=1; m<64; m<<=1) mx = fmaxf(mx, __shfl_xor(mx, m));
  if ((tid & 63) == 0) red[tid >> 6] = mx;
  __syncthreads();
  mx = fmaxf(fmaxf(red[0], red[1]), fmaxf(red[2], red[3]));
  float e0 = (tid       < L) ? __expf(v0 - mx) : 0.f;
  float e1 = (tid + 256 < L) ? __expf(v1 - mx) : 0.f;
  float s = e0 + e1;
  for (int m=1; m<64; m<<=1) s += __shfl_xor(s, m);
  if ((tid & 63) == 0) red2[tid >> 6] = s;
  __syncthreads();
  s = red2[0] + red2[1] + red2[2] + red2[3];
  float inv = 1.f / s;
  attn[b*512 + tid]       = e0 * inv;
  attn[b*512 + tid + 256] = e1 * inv;
}

__global__ void context_kernel(const ushort* __restrict__ enc,
                               const float* __restrict__ attn,
                               float* __restrict__ ctx){
  int b = blockIdx.x, tid = threadIdx.x;
  float a6[6] = {0.f,0.f,0.f,0.f,0.f,0.f};
  for (int t=0; t<512; t++){
    float a = attn[b*512 + t];
    if (a != 0.f){
      const ushort* e = enc + ((size_t)b*512 + t)*1536;
      #pragma unroll
      for (int i=0;i<6;i++) a6[i] += a * bf2f(e[tid + i*256]);
    }
  }
  #pragma unroll
  for (int i=0;i<6;i++) ctx[b*1536 + tid + i*256] = a6[i];
}

__global__ void post_kernel(const float* __restrict__ ctx,
                            const float* __restrict__ Wp,
                            const float* __restrict__ bp,
                            float* __restrict__ post){
  int b = blockIdx.x;
  int j = blockIdx.y*256 + threadIdx.x;
  float acc = bp[j];
  const float* c = ctx + b*1536;
  for (int k=0;k<1536;k++) acc += c[k] * Wp[(size_t)k*1536 + j];
  post[b*1536 + j] = acc;
}

__global__ void intents_kernel(const float* __restrict__ post,
                               const float* __restrict__ Wi,
                               const float* __restrict__ bi,
                               float* __restrict__ out){
  int b = blockIdx.x, j = threadIdx.x;
  if (j < 60){
    float acc = bi[j];
    const float* p = post + b*1536;
    for (int k=0;k<1536;k++) acc += p[k] * Wi[k*60 + j];
    out[b*60 + j] = acc;
  }
}

// ------------------------- host side ---------------------------------------
extern "C" void kernel_launch(void* const* d_in, const int* in_sizes, int n_in,
                              void* d_out, int out_size, void* d_ws, size_t ws_size,
                              hipStream_t stream) {
  const float* lat    = (const float*)d_in[0];
  const int*   nf     = (const int*)  d_in[1];
  const float* W_reg  = (const float*)d_in[3];
  const float* b_reg  = (const float*)d_in[4];
  const float* Wi0f   = (const float*)d_in[5];
  const float* Wh0f   = (const float*)d_in[6];
  const float* b0f    = (const float*)d_in[7];
  const float* Wi0b   = (const float*)d_in[8];
  const float* Wh0b   = (const float*)d_in[9];
  const float* b0b    = (const float*)d_in[10];
  const float* Wi1f   = (const float*)d_in[11];
  const float* Wh1f   = (const float*)d_in[12];
  const float* b1f    = (const float*)d_in[13];
  const float* Wi1b   = (const float*)d_in[14];
  const float* Wh1b   = (const float*)d_in[15];
  const float* b1b    = (const float*)d_in[16];
  const float* W_keys = (const float*)d_in[17];
  const float* W_en   = (const float*)d_in[18];
  const float* W_post = (const float*)d_in[19];
  const float* b_post = (const float*)d_in[20];
  const float* W_int  = (const float*)d_in[21];
  const float* b_int  = (const float*)d_in[22];
  float* out = (float*)d_out;

  char* wsp = (char*)d_ws;
  auto alloc = [&](size_t n) -> char* {
    char* p = wsp; wsp += (n + 255) & ~(size_t)255; return p;
  };
  ushort* enc1 = (ushort*)alloc((size_t)MTOT*1536*2);
  ushort* enc2 = (ushort*)alloc((size_t)MTOT*1536*2);
  ushort* wip  = (ushort*)alloc((size_t)2*96*32*1536*2);
  ushort* wh_fh = (ushort*)alloc((size_t)2359296*2);
  ushort* wh_fl = (ushort*)alloc((size_t)2359296*2);
  ushort* wh_bh = (ushort*)alloc((size_t)2359296*2);
  ushort* wh_bl = (ushort*)alloc((size_t)2359296*2);
  ushort* sTh  = (ushort*)alloc((size_t)3072*1024*2);
  ushort* sTl  = (ushort*)alloc((size_t)3072*1024*2);
  float*  sWc  = (float*) alloc((size_t)1024*3072*4);
  float*  bc   = (float*) alloc((size_t)2*3072*4);
  char* state0 = wsp;
  ushort* hstate = (ushort*)alloc((size_t)8*49152*2);
  float*  cstate = (float*) alloc((size_t)2*49152*4);
  int*    barr   = (int*)   alloc(1024);
  size_t state_bytes = (size_t)((char*)wsp - state0);
  float* scores = (float*)alloc((size_t)MTOT*4);
  float* attn   = (float*)alloc((size_t)MTOT*4);
  float* ctx    = (float*)alloc((size_t)NB*1536*4);
  float* postb  = (float*)alloc((size_t)NB*1536*4);
  size_t used = (size_t)(wsp - (char*)d_ws);
  fprintf(stderr, "[kernel_launch] ws_size=%zu used=%zu\n", ws_size, used);
  (void)in_sizes; (void)n_in; (void)out_size;

  int state_words = (int)(state_bytes / 4);

  // ---- layer 0 prep: Wc = W_reg @ Wi0{f,b}, pack; Wh0 packs; bias comb ----
  hipLaunchKernelGGL(zero_kernel, dim3(512), dim3(256), 0, stream, (uint32_t*)state0, state_words);
  hipLaunchKernelGGL(transpose_split_kernel, dim3(16,48), dim3(256), 0, stream, Wi0f, sTh, sTl, 1024, 3072);
  hipLaunchKernelGGL((gemm_kernel<0,0>), dim3(8*24), dim3(256), 0, stream,
                     (const void*)W_reg, sTh, sTl, (const float*)nullptr, sWc,
                     (const float*)nullptr, (float*)nullptr, 1024, 3072, 1024);
  hipLaunchKernelGGL(pack_wi_kernel, dim3(4608), dim3(256), 0, stream, sWc, wip, 1024);
  hipLaunchKernelGGL(transpose_split_kernel, dim3(16,48), dim3(256), 0, stream, Wi0b, sTh, sTl, 1024, 3072);
  hipLaunchKernelGGL((gemm_kernel<0,0>), dim3(8*24), dim3(256), 0, stream,
                     (const void*)W_reg, sTh, sTl, (const float*)nullptr, sWc,
                     (const float*)nullptr, (float*)nullptr, 1024, 3072, 1024);
  hipLaunchKernelGGL(pack_wi_kernel, dim3(4608), dim3(256), 0, stream, sWc, wip + (size_t)96*32*1024, 1024);
  hipLaunchKernelGGL(whpack_kernel, dim3(9216), dim3(256), 0, stream, Wh0f, wh_fh, wh_fl);
  hipLaunchKernelGGL(whpack_kernel, dim3(9216), dim3(256), 0, stream, Wh0b, wh_bh, wh_bl);
  hipLaunchKernelGGL(bias_comb_kernel, dim3(12,2), dim3(256), 0, stream, b0f, b0b, Wi0f, Wi0b, b_reg, 1024, bc);
  // ---- BiLSTM layer 0: lat (fp32) -> enc1 (bf16) ----
  hipLaunchKernelGGL((recur_fused<32,1>), dim3(192), dim3(256), 0, stream,
                     (const void*)lat, wip, wh_fh, wh_fl, wh_bh, wh_bl, bc,
                     enc1, nf, hstate, cstate, barr);
  // ---- layer 1 prep ----
  hipLaunchKernelGGL(zero_kernel, dim3(512), dim3(256), 0, stream, (uint32_t*)state0, state_words);
  hipLaunchKernelGGL(pack_wi_kernel, dim3(4608), dim3(256), 0, stream, Wi1f, wip, 1536);
  hipLaunchKernelGGL(pack_wi_kernel, dim3(4608), dim3(256), 0, stream, Wi1b, wip + (size_t)96*32*1536, 1536);
  hipLaunchKernelGGL(whpack_kernel, dim3(9216), dim3(256), 0, stream, Wh1f, wh_fh, wh_fl);
  hipLaunchKernelGGL(whpack_kernel, dim3(9216), dim3(256), 0, stream, Wh1b, wh_bh, wh_bl);
  hipLaunchKernelGGL(bias_comb_kernel, dim3(12,2), dim3(256), 0, stream, b1f, b1b,
                     (const float*)nullptr, (const float*)nullptr, b_reg, 0, bc);
  // ---- BiLSTM layer 1: enc1 (bf16) -> enc2 (bf16) ----
  hipLaunchKernelGGL((recur_fused<48,0>), dim3(192), dim3(256), 0, stream,
                     (const void*)enc1, wip, wh_fh, wh_fl, wh_bh, wh_bl, bc,
                     enc2, nf, hstate, cstate, barr);
  // ---- attention: scores = sum_col tanh(enc2@Wk)*We ----
  hipLaunchKernelGGL(zero_kernel, dim3(128), dim3(256), 0, stream, (uint32_t*)scores, MTOT);
  hipLaunchKernelGGL(transpose_split_kernel, dim3(24,24), dim3(256), 0, stream, W_keys, sTh, sTl, 1536, 1536);
  hipLaunchKernelGGL((gemm_kernel<2,1>), dim3(256*12), dim3(256), 0, stream,
                     (const void*)enc2, sTh, sTl, (const float*)nullptr, (float*)nullptr,
                     W_en, scores, MTOT, 1536, 1536);
  hipLaunchKernelGGL(softmax_kernel, dim3(64), dim3(256), 0, stream, scores, nf, attn);
  hipLaunchKernelGGL(context_kernel, dim3(64), dim3(256), 0, stream, enc2, attn, ctx);
  hipLaunchKernelGGL(post_kernel, dim3(64,6), dim3(256), 0, stream, ctx, W_post, b_post, postb);
  hipLaunchKernelGGL(intents_kernel, dim3(64), dim3(64), 0, stream, postb, W_int, b_int, out);
}

// Round 3
// 30291.577 us; speedup vs baseline: 2.0501x; 2.0501x over previous
//
#include <hip/hip_runtime.h>
#include <cstdint>
#include <cstddef>

// ---------------------------------------------------------------------------
// IntentClassifier on MI355X.
//   dense(1024->1024) folded into layer0 Wi (Wc = W_reg@Wi0)
//   2x BiLSTM (H=768): persistent grid-barrier kernel, x@Wi fused via LDS-
//     resident Wi slice (1-pass bf16), h@Wh via register-pinned split-bf16
//     (3-pass). 192 wgs, LDS >80KB => 1 block/CU => co-residency structural.
//   R3 change: NO cache-maintenance ops in the recurrent loop. All cross-wg
//   h-state goes through RELAXED agent-scope atomics (sc1 -> Infinity Cache,
//   the coherent point). threadfence (L2 wb+inv per step) and ACQUIRE spins
//   (L2 inv per poll) removed -- they were 57.7us/step of stall.
// ---------------------------------------------------------------------------

typedef __attribute__((ext_vector_type(8))) short s8v;   // 8 x bf16
typedef __attribute__((ext_vector_type(4))) short s4v;
typedef __attribute__((ext_vector_type(4))) float f4v;

#define MFMA16(a,b,c) __builtin_amdgcn_mfma_f32_16x16x32_bf16((a),(b),(c),0,0,0)

#define NB   64
#define NT   512
#define MTOT (NB*NT)     // 32768 rows

__device__ __forceinline__ ushort f2bf(float x){
  uint32_t u = __float_as_uint(x);
  uint32_t r = (u + 0x7FFFu + ((u >> 16) & 1u)) >> 16;   // RNE
  return (ushort)r;
}
__device__ __forceinline__ float bf2f(ushort h){
  return __uint_as_float(((uint32_t)h) << 16);
}
__device__ __forceinline__ float fsig(float x){
  x = fminf(30.f, fmaxf(-30.f, x));
  return 1.f / (1.f + __expf(-x));
}
__device__ __forceinline__ float ftanh(float x){
  x = fminf(15.f, fmaxf(-15.f, x));
  float e = __expf(2.f * x);
  return (e - 1.f) / (e + 1.f);
}

// ---- coherent (Infinity-Cache) access helpers: relaxed agent atomics ------
__device__ __forceinline__ s8v ldh16(const ushort* p){
  union { s8v v; uint64_t q[2]; } u;
  uint64_t* a = (uint64_t*)p;
  u.q[0] = __hip_atomic_load(a,     __ATOMIC_RELAXED, __HIP_MEMORY_SCOPE_AGENT);
  u.q[1] = __hip_atomic_load(a + 1, __ATOMIC_RELAXED, __HIP_MEMORY_SCOPE_AGENT);
  return u.v;
}
__device__ __forceinline__ uint32_t ldh32(const ushort* p){
  return __hip_atomic_load((uint32_t*)p, __ATOMIC_RELAXED, __HIP_MEMORY_SCOPE_AGENT);
}
__device__ __forceinline__ void sth32(ushort* p, uint32_t v){
  __hip_atomic_store((uint32_t*)p, v, __ATOMIC_RELAXED, __HIP_MEMORY_SCOPE_AGENT);
}

// ------------------------- weight prep kernels -----------------------------
__global__ void transpose_split_kernel(const float* __restrict__ B,
                                       ushort* __restrict__ Th,
                                       ushort* __restrict__ Tl,
                                       int K, int N){
  __shared__ float tile[64][65];
  int k0 = blockIdx.x * 64, n0 = blockIdx.y * 64;
  for (int i = threadIdx.x; i < 4096; i += 256){
    int r = i >> 6, c = i & 63;
    tile[r][c] = B[(size_t)(k0 + r) * N + (n0 + c)];
  }
  __syncthreads();
  for (int i = threadIdx.x; i < 4096; i += 256){
    int nr = i >> 6, kc = i & 63;
    float x = tile[kc][nr];
    ushort h = f2bf(x);
    ushort lo = f2bf(x - bf2f(h));
    size_t o = (size_t)(n0 + nr) * K + (k0 + kc);
    Th[o] = h; Tl[o] = lo;
  }
}

// Wh (768,3072) fp32 -> fragment-packed bf16 hi/lo: [wgd(96)][nt(2)][kt(24)][lane(64)][j(8)]
__global__ void whpack_kernel(const float* __restrict__ Wh,
                              ushort* __restrict__ Ph, ushort* __restrict__ Pl){
  int idx = blockIdx.x * 256 + threadIdx.x;     // 2,359,296 total
  int j    = idx & 7;
  int lane = (idx >> 3) & 63;
  int kt   = (idx >> 9) % 24;
  int rest = idx / (24 * 512);                  // wgd*2 + nt
  int nt   = rest & 1;
  int wgd  = rest >> 1;
  int c    = lane & 15;
  int gate = nt * 2 + (c >> 3);
  int q    = wgd * 8 + (c & 7);
  int k    = kt * 32 + (lane >> 4) * 8 + j;
  float x = Wh[(size_t)k * 3072 + gate * 768 + q];
  ushort h = f2bf(x);
  Ph[idx] = h;
  Pl[idx] = f2bf(x - bf2f(h));
}

// W (K,3072) fp32 -> packed bf16 [wgd(96)][n(32)][k(K)], col(n)=(n>>3)*768+wgd*8+(n&7)
__global__ void pack_wi_kernel(const float* __restrict__ W,
                               ushort* __restrict__ dst, int K){
  int total = 96 * 32 * K;
  for (int idx = blockIdx.x * 256 + threadIdx.x; idx < total; idx += gridDim.x * 256){
    int k = idx % K;
    int rest = idx / K;            // wgd*32 + n
    int n = rest & 31, wgd = rest >> 5;
    float x = W[(size_t)k * 3072 + (n >> 3) * 768 + wgd * 8 + (n & 7)];
    dst[idx] = f2bf(x);
  }
}

// bc[d][c] = b_d[c] + sum_k breg[k]*W_d[k,c]   (W=nullptr -> plain copy)
__global__ void bias_comb_kernel(const float* __restrict__ bf, const float* __restrict__ bb,
                                 const float* __restrict__ Wf, const float* __restrict__ Wb,
                                 const float* __restrict__ breg, int Kb,
                                 float* __restrict__ bc){
  int c = blockIdx.x * 256 + threadIdx.x;   // < 3072
  int d = blockIdx.y;
  const float* b = d ? bb : bf;
  const float* W = d ? Wb : Wf;
  float acc = b[c];
  if (W){
    for (int k = 0; k < Kb; k++) acc += breg[k] * W[(size_t)k * 3072 + c];
  }
  bc[d * 3072 + c] = acc;
}

__global__ void zero_kernel(uint32_t* __restrict__ p, int n){
  for (int i = blockIdx.x * 256 + threadIdx.x; i < n; i += gridDim.x * 256)
    p[i] = 0u;
}

// ------------------------- split-bf16 GEMM ---------------------------------
// MODE 0: C = A@B + bias (fp32 out).   MODE 2: scores[row] += sum_col tanh(C)*We[col]
// ABF 0: A fp32 (split in-kernel, 3-pass).  ABF 1: A bf16 (2-pass)
template<int MODE, int ABF>
__global__ __launch_bounds__(256, 2) void gemm_kernel(
    const void* __restrict__ Araw, const ushort* __restrict__ Bh,
    const ushort* __restrict__ Bl, const float* __restrict__ bias,
    float* __restrict__ outF,
    const float* __restrict__ We, float* __restrict__ scores,
    int M, int N, int K)
{
  __shared__ short lA_h[128*40], lA_l[128*40], lB_h[128*40], lB_l[128*40];
  int tid = threadIdx.x, l = tid & 63, w = tid >> 6;
  int wr = w >> 1, wc = w & 1;
  int nbM = M >> 7;
  int mblk = blockIdx.x % nbM, nblk = blockIdx.x / nbM;
  f4v acc[4][4];
  for (int i=0;i<4;i++) for (int j=0;j<4;j++) acc[i][j] = (f4v){0.f,0.f,0.f,0.f};
  int nk = K >> 5;
  const ushort* Bhb = Bh + (size_t)nblk*128*K;
  const ushort* Blb = Bl + (size_t)nblk*128*K;
  int mrow = l & 15, koff = (l >> 4) * 8;
  for (int kt = 0; kt < nk; kt++){
    if (ABF == 0){   // fp32 A -> split hi/lo
      const float* Ab = (const float*)Araw + (size_t)mblk*128*K;
      int c4 = (l & 7) * 4;
      #pragma unroll
      for (int i=0;i<4;i++){
        int r = (w*4 + i)*8 + (l >> 3);
        const float* p = Ab + (size_t)r*K + kt*32 + c4;
        float4 v = *(const float4*)p;
        float xs[4] = {v.x, v.y, v.z, v.w};
        s4v hv, lv;
        #pragma unroll
        for (int j=0;j<4;j++){
          ushort hh = f2bf(xs[j]);
          hv[j] = (short)hh;
          lv[j] = (short)f2bf(xs[j] - bf2f(hh));
        }
        *(s4v*)&lA_h[r*40 + c4] = hv;
        *(s4v*)&lA_l[r*40 + c4] = lv;
      }
    } else {         // bf16 A
      const ushort* Ab = (const ushort*)Araw + (size_t)mblk*128*K;
      int k8 = (l & 3) * 8;
      #pragma unroll
      for (int i=0;i<2;i++){
        int r = (w*2 + i)*16 + (l >> 2);
        *(s8v*)&lA_h[r*40 + k8] = *(const s8v*)(Ab + (size_t)r*K + kt*32 + k8);
      }
    }
    {
      int k8 = (l & 3) * 8;
      #pragma unroll
      for (int i=0;i<2;i++){
        int r = (w*2 + i)*16 + (l >> 2);
        size_t o = (size_t)r*K + kt*32 + k8;
        *(s8v*)&lB_h[r*40 + k8] = *(const s8v*)(Bhb + o);
        *(s8v*)&lB_l[r*40 + k8] = *(const s8v*)(Blb + o);
      }
    }
    __syncthreads();
    s8v ah[4], al[4], bh[4], bl[4];
    #pragma unroll
    for (int mt=0;mt<4;mt++){
      int base = (wr*64 + mt*16 + mrow)*40 + koff;
      ah[mt] = *(s8v*)&lA_h[base];
      if (ABF == 0) al[mt] = *(s8v*)&lA_l[base];
    }
    #pragma unroll
    for (int nt=0;nt<4;nt++){
      int base = (wc*64 + nt*16 + mrow)*40 + koff;
      bh[nt] = *(s8v*)&lB_h[base];
      bl[nt] = *(s8v*)&lB_l[base];
    }
    #pragma unroll
    for (int mt=0;mt<4;mt++)
      #pragma unroll
      for (int nt=0;nt<4;nt++){
        acc[mt][nt] = MFMA16(ah[mt], bh[nt], acc[mt][nt]);
        acc[mt][nt] = MFMA16(ah[mt], bl[nt], acc[mt][nt]);
        if (ABF == 0) acc[mt][nt] = MFMA16(al[mt], bh[nt], acc[mt][nt]);
      }
    __syncthreads();
  }
  // epilogue. C/D layout: col = lane&15, row = (lane>>4)*4 + r
  if (MODE == 2){
    float pre[4][4];
    #pragma unroll
    for (int mt=0;mt<4;mt++) for (int r=0;r<4;r++) pre[mt][r] = 0.f;
    #pragma unroll
    for (int nt=0;nt<4;nt++){
      int colg = nblk*128 + wc*64 + nt*16 + (l & 15);
      float we = We[colg];
      #pragma unroll
      for (int mt=0;mt<4;mt++)
        #pragma unroll
        for (int r=0;r<4;r++)
          pre[mt][r] += ftanh(acc[mt][nt][r]) * we;
    }
    #pragma unroll
    for (int mt=0;mt<4;mt++)
      #pragma unroll
      for (int r=0;r<4;r++){
        float v = pre[mt][r];
        v += __shfl_xor(v, 1); v += __shfl_xor(v, 2);
        v += __shfl_xor(v, 4); v += __shfl_xor(v, 8);
        if ((l & 15) == 0){
          int rowg = mblk*128 + wr*64 + mt*16 + (l>>4)*4 + r;
          atomicAdd(scores + rowg, v);
        }
      }
  } else {
    #pragma unroll
    for (int mt=0;mt<4;mt++)
      #pragma unroll
      for (int nt=0;nt<4;nt++){
        int rowg0 = mblk*128 + wr*64 + mt*16 + (l>>4)*4;
        int colg  = nblk*128 + wc*64 + nt*16 + (l & 15);
        float bv = bias ? bias[colg] : 0.f;
        #pragma unroll
        for (int r=0;r<4;r++){
          float v = acc[mt][nt][r] + bv;
          outF[(size_t)(rowg0 + r)*N + colg] = v;
        }
      }
  }
}

// ------------------------- fused persistent BiLSTM -------------------------
// grid = 192 x 256. dir = bx&1, wgd = bx>>1 owns 8 h-cols (32 z-cols).
// All cross-wg h traffic: relaxed agent atomics (sc1 -> IC). No fences.
template<int NKT, int XF32>
__global__ __launch_bounds__(256, 1) void recur_fused(
    const void* __restrict__ xsrc, const ushort* __restrict__ wip,
    const ushort* __restrict__ whfh, const ushort* __restrict__ whfl,
    const ushort* __restrict__ whbh, const ushort* __restrict__ whbl,
    const float* __restrict__ bias2, ushort* __restrict__ enc,
    const int* __restrict__ nf, ushort* __restrict__ hstate,
    float* __restrict__ cstate, int* __restrict__ barr)
{
  constexpr int K  = NKT * 32;
  constexpr int KP = K + 8;
  constexpr int KPW = NKT / 4;
  __shared__ ushort wilds[32 * KP];
  __shared__ float zlds[9216];        // [w][mt][nt][col16][row pad18]
  __shared__ float bcs[32];
  __shared__ int nfs[64];
  __shared__ int lmaxs[4];
  const int tid = threadIdx.x, l = tid & 63, w = tid >> 6;
  const int dir = blockIdx.x & 1, wgd = blockIdx.x >> 1, wq0 = wgd * 8;

  { // stage this wg's Wi slice into LDS
    const ushort* wsrc = wip + ((size_t)(dir*96 + wgd)) * 32 * K;
    for (int idx = tid; idx < 32 * (K/8); idx += 256){
      int row = idx / (K/8);
      int c8  = (idx - row * (K/8)) * 8;
      *(s8v*)&wilds[row*KP + c8] = *(const s8v*)(wsrc + (size_t)row*K + c8);
    }
  }
  if (tid < 64) nfs[tid] = nf[tid];
  if (tid < 32) bcs[tid] = bias2[dir*3072 + (tid>>3)*768 + wq0 + (tid&7)];
  __syncthreads();
  if (tid < 4){
    int m = 0;
    for (int i=0;i<16;i++) m = max(m, nfs[tid*16 + i]);
    lmaxs[tid] = m;
  }
  __syncthreads();
  int lm[4], Lbl[4];
  #pragma unroll
  for (int mt=0;mt<4;mt++){ lm[mt] = lmaxs[mt]; Lbl[mt] = nfs[mt*16 + (l&15)]; }
  // gate cells: thread owns 2 ADJACENT cols (q0=2*qp, q0+1) of batch gb
  const int gb = tid >> 2, qp = tid & 3, q0 = qp*2;
  const int gL = nfs[gb];
  const int ghidx = gb*768 + wq0 + q0;          // dword-aligned (q0 even)
  float* cst = cstate + dir * 49152;

  const ushort* wph = dir ? whbh : whfh;
  const ushort* wpl = dir ? whbl : whfl;
  s8v whh[2][6], whl[2][6];
  #pragma unroll
  for (int nt=0;nt<2;nt++)
    for (int i=0;i<6;i++){
      size_t o = ((size_t)((wgd*2 + nt)*24 + (w*6 + i)) * 64 + l) * 8;
      whh[nt][i] = *(const s8v*)(wph + o);
      whl[nt][i] = *(const s8v*)(wpl + o);
    }

  f4v aX[4][2];
  auto xpart = [&](int t){
    #pragma unroll
    for (int mt=0;mt<4;mt++){ aX[mt][0]=(f4v){0.f,0.f,0.f,0.f}; aX[mt][1]=(f4v){0.f,0.f,0.f,0.f}; }
    #pragma unroll
    for (int i=0;i<KPW;i++){
      int kt = w*KPW + i;
      int kc = kt*32 + (l>>4)*8;
      s8v bf0 = *(const s8v*)&wilds[(l & 15)*KP + kc];
      s8v bf1 = *(const s8v*)&wilds[(16 + (l & 15))*KP + kc];
      #pragma unroll
      for (int mt=0;mt<4;mt++){
        if (t >= lm[mt]) continue;
        int bb = mt*16 + (l & 15);
        int r = t;
        if (dir && t < Lbl[mt]) r = Lbl[mt] - 1 - t;
        size_t off = ((size_t)bb*512 + r)*K + kc;
        s8v a;
        if constexpr (XF32){
          const float* xf = (const float*)xsrc;
          float4 u0 = *(const float4*)(xf + off);
          float4 u1 = *(const float4*)(xf + off + 4);
          a[0]=(short)f2bf(u0.x); a[1]=(short)f2bf(u0.y);
          a[2]=(short)f2bf(u0.z); a[3]=(short)f2bf(u0.w);
          a[4]=(short)f2bf(u1.x); a[5]=(short)f2bf(u1.y);
          a[6]=(short)f2bf(u1.z); a[7]=(short)f2bf(u1.w);
        } else {
          a = *(const s8v*)((const ushort*)xsrc + off);
        }
        aX[mt][0] = MFMA16(a, bf0, aX[mt][0]);
        aX[mt][1] = MFMA16(a, bf1, aX[mt][1]);
      }
    }
  };
  xpart(0);
  const int leaf = (blockIdx.x >> 3) * 32;   // 24 leaves, 128B apart

  for (int t = 0; t < 512; t++){
    if (t > 0 && tid == 0){
      while (__hip_atomic_load(barr + 800, __ATOMIC_RELAXED, __HIP_MEMORY_SCOPE_AGENT) < t)
        __builtin_amdgcn_s_sleep(2);
    }
    __syncthreads();
    const int p = t & 1;
    const ushort* hr_hi = hstate + ((size_t)((dir*2 + p)*2 + 0)) * 49152;
    const ushort* hr_lo = hstate + ((size_t)((dir*2 + p)*2 + 1)) * 49152;
    ushort* hw_hi = hstate + ((size_t)((dir*2 + (p^1))*2 + 0)) * 49152;
    ushort* hw_lo = hstate + ((size_t)((dir*2 + (p^1))*2 + 1)) * 49152;

    f4v acc[4][2];
    #pragma unroll
    for (int mt=0;mt<4;mt++){ acc[mt][0] = aX[mt][0]; acc[mt][1] = aX[mt][1]; }

    #pragma unroll
    for (int i=0;i<6;i++){
      int kc = (w*6 + i)*32 + (l>>4)*8;
      #pragma unroll
      for (int mt=0;mt<4;mt++){
        if (t >= lm[mt]) continue;
        size_t o = (size_t)(mt*16 + (l & 15))*768 + kc;
        s8v ahh = ldh16(hr_hi + o);
        s8v ahl = ldh16(hr_lo + o);
        acc[mt][0] = MFMA16(ahh, whh[0][i], acc[mt][0]);
        acc[mt][0] = MFMA16(ahh, whl[0][i], acc[mt][0]);
        acc[mt][0] = MFMA16(ahl, whh[0][i], acc[mt][0]);
        acc[mt][1] = MFMA16(ahh, whh[1][i], acc[mt][1]);
        acc[mt][1] = MFMA16(ahh, whl[1][i], acc[mt][1]);
        acc[mt][1] = MFMA16(ahl, whh[1][i], acc[mt][1]);
      }
    }
    #pragma unroll
    for (int mt=0;mt<4;mt++)
      #pragma unroll
      for (int nt=0;nt<2;nt++){
        int base = (((w*4 + mt)*2 + nt)*16 + (l & 15))*18 + (l>>4)*4;
        zlds[base+0] = acc[mt][nt][0];
        zlds[base+1] = acc[mt][nt][1];
        zlds[base+2] = acc[mt][nt][2];
        zlds[base+3] = acc[mt][nt][3];
      }
    __syncthreads();
    { // gates: 2 adjacent cols per thread
      if (t < gL){
        int mt = gb >> 4, row = gb & 15;
        float nhv[2];
        #pragma unroll
        for (int e=0;e<2;e++){
          int q = q0 + e;
          float zg4[4];
          #pragma unroll
          for (int g=0; g<4; g++){
            int nt = g >> 1, c = (g & 1)*8 + q;
            int zb = ((mt*2 + nt)*16 + c)*18 + row;
            zg4[g] = zlds[zb] + zlds[zb+2304] + zlds[zb+4608] + zlds[zb+6912] + bcs[g*8 + q];
          }
          float co = cst[ghidx + e];
          float nc = fsig(zg4[1])*co + fsig(zg4[0])*ftanh(zg4[2]);
          float nh = fsig(zg4[3])*ftanh(nc);
          cst[ghidx + e] = nc;
          nhv[e] = nh;
        }
        ushort h0h = f2bf(nhv[0]), h1h = f2bf(nhv[1]);
        ushort h0l = f2bf(nhv[0] - bf2f(h0h)), h1l = f2bf(nhv[1] - bf2f(h1h));
        sth32(hw_hi + ghidx, (uint32_t)h0h | ((uint32_t)h1h << 16));
        sth32(hw_lo + ghidx, (uint32_t)h0l | ((uint32_t)h1l << 16));
        int r = dir ? (gL - 1 - t) : t;
        *(uint32_t*)&enc[((size_t)gb*512 + r)*1536 + dir*768 + wq0 + q0] =
            (uint32_t)h0h | ((uint32_t)h1h << 16);
      } else {
        sth32(hw_hi + ghidx, ldh32(hr_hi + ghidx));
        sth32(hw_lo + ghidx, ldh32(hr_lo + ghidx));
      }
    }
    __syncthreads();   // drains all waves' sc1 stores (vmcnt) before arrive
    if (tid == 0){     // monotonic 2-level tree: 24 leaves x 8, root, gen
      int prev = __hip_atomic_fetch_add(barr + leaf, 1, __ATOMIC_RELAXED, __HIP_MEMORY_SCOPE_AGENT);
      if (prev == 8*(t+1) - 1){
        int p2 = __hip_atomic_fetch_add(barr + 768, 1, __ATOMIC_RELAXED, __HIP_MEMORY_SCOPE_AGENT);
        if (p2 == 24*(t+1) - 1)
          __hip_atomic_store(barr + 800, t + 1, __ATOMIC_RELAXED, __HIP_MEMORY_SCOPE_AGENT);
      }
    }
    if (t < 511) xpart(t + 1);   // prefetch next x@Wi while others arrive
  }
}

// ------------------------- attention tail ----------------------------------
__global__ void softmax_kernel(const float* __restrict__ scores,
                               const int* __restrict__ nf,
                               float* __restrict__ attn){
  __shared__ float red[4], red2[4];
  int b = blockIdx.x, tid = threadIdx.x;
  int L = nf[b];
  float v0 = (tid       < L) ? scores[b*512 + tid]       : -1e30f;
  float v1 = (tid + 256 < L) ? scores[b*512 + tid + 256] : -1e30f;
  float mx = fmaxf(v0, v1);
  for (int m=1; m<64; m<<=1) mx = fmaxf(mx, __shfl_xor(mx, m));
  if ((tid & 63) == 0) red[tid >> 6] = mx;
  __syncthreads();
  mx = fmaxf(fmaxf(red[0], red[1]), fmaxf(red[2], red[3]));
  float e0 = (tid       < L) ? __expf(v0 - mx) : 0.f;
  float e1 = (tid + 256 < L) ? __expf(v1 - mx) : 0.f;
  float s = e0 + e1;
  for (int m=1; m<64; m<<=1) s += __shfl_xor(s, m);
  if ((tid & 63) == 0) red2[tid >> 6] = s;
  __syncthreads();
  s = red2[0] + red2[1] + red2[2] + red2[3];
  float inv = 1.f / s;
  attn[b*512 + tid]       = e0 * inv;
  attn[b*512 + tid + 256] = e1 * inv;
}

__global__ void context_kernel(const ushort* __restrict__ enc,
                               const float* __restrict__ attn,
                               float* __restrict__ ctx){
  int b = blockIdx.x, tid = threadIdx.x;
  float a6[6] = {0.f,0.f,0.f,0.f,0.f,0.f};
  for (int t=0; t<512; t++){
    float a = attn[b*512 + t];
    if (a != 0.f){
      const ushort* e = enc + ((size_t)b*512 + t)*1536;
      #pragma unroll
      for (int i=0;i<6;i++) a6[i] += a * bf2f(e[tid + i*256]);
    }
  }
  #pragma unroll
  for (int i=0;i<6;i++) ctx[b*1536 + tid + i*256] = a6[i];
}

__global__ void post_kernel(const float* __restrict__ ctx,
                            const float* __restrict__ Wp,
                            const float* __restrict__ bp,
                            float* __restrict__ post){
  int b = blockIdx.x;
  int j = blockIdx.y*256 + threadIdx.x;
  float acc = bp[j];
  const float* c = ctx + b*1536;
  for (int k=0;k<1536;k++) acc += c[k] * Wp[(size_t)k*1536 + j];
  post[b*1536 + j] = acc;
}

__global__ void intents_kernel(const float* __restrict__ post,
                               const float* __restrict__ Wi,
                               const float* __restrict__ bi,
                               float* __restrict__ out){
  int b = blockIdx.x, j = threadIdx.x;
  if (j < 60){
    float acc = bi[j];
    const float* p = post + b*1536;
    for (int k=0;k<1536;k++) acc += p[k] * Wi[k*60 + j];
    out[b*60 + j] = acc;
  }
}

// ------------------------- host side ---------------------------------------
extern "C" void kernel_launch(void* const* d_in, const int* in_sizes, int n_in,
                              void* d_out, int out_size, void* d_ws, size_t ws_size,
                              hipStream_t stream) {
  const float* lat    = (const float*)d_in[0];
  const int*   nf     = (const int*)  d_in[1];
  const float* W_reg  = (const float*)d_in[3];
  const float* b_reg  = (const float*)d_in[4];
  const float* Wi0f   = (const float*)d_in[5];
  const float* Wh0f   = (const float*)d_in[6];
  const float* b0f    = (const float*)d_in[7];
  const float* Wi0b   = (const float*)d_in[8];
  const float* Wh0b   = (const float*)d_in[9];
  const float* b0b    = (const float*)d_in[10];
  const float* Wi1f   = (const float*)d_in[11];
  const float* Wh1f   = (const float*)d_in[12];
  const float* b1f    = (const float*)d_in[13];
  const float* Wi1b   = (const float*)d_in[14];
  const float* Wh1b   = (const float*)d_in[15];
  const float* b1b    = (const float*)d_in[16];
  const float* W_keys = (const float*)d_in[17];
  const float* W_en   = (const float*)d_in[18];
  const float* W_post = (const float*)d_in[19];
  const float* b_post = (const float*)d_in[20];
  const float* W_int  = (const float*)d_in[21];
  const float* b_int  = (const float*)d_in[22];
  float* out = (float*)d_out;

  char* wsp = (char*)d_ws;
  auto alloc = [&](size_t n) -> char* {
    char* p = wsp; wsp += (n + 255) & ~(size_t)255; return p;
  };
  ushort* enc1 = (ushort*)alloc((size_t)MTOT*1536*2);
  ushort* enc2 = (ushort*)alloc((size_t)MTOT*1536*2);
  ushort* wip  = (ushort*)alloc((size_t)2*96*32*1536*2);
  ushort* wh_fh = (ushort*)alloc((size_t)2359296*2);
  ushort* wh_fl = (ushort*)alloc((size_t)2359296*2);
  ushort* wh_bh = (ushort*)alloc((size_t)2359296*2);
  ushort* wh_bl = (ushort*)alloc((size_t)2359296*2);
  ushort* sTh  = (ushort*)alloc((size_t)3072*1024*2);
  ushort* sTl  = (ushort*)alloc((size_t)3072*1024*2);
  float*  sWc  = (float*) alloc((size_t)1024*3072*4);
  float*  bc   = (float*) alloc((size_t)2*3072*4);
  char* state0 = wsp;
  ushort* hstate = (ushort*)alloc((size_t)8*49152*2);
  float*  cstate = (float*) alloc((size_t)2*49152*4);
  int*    barr   = (int*)   alloc(4096);
  size_t state_bytes = (size_t)((char*)wsp - state0);
  float* scores = (float*)alloc((size_t)MTOT*4);
  float* attn   = (float*)alloc((size_t)MTOT*4);
  float* ctx    = (float*)alloc((size_t)NB*1536*4);
  float* postb  = (float*)alloc((size_t)NB*1536*4);
  (void)in_sizes; (void)n_in; (void)out_size; (void)ws_size;

  int state_words = (int)(state_bytes / 4);

  // ---- layer 0 prep: Wc = W_reg @ Wi0{f,b}, pack; Wh0 packs; bias comb ----
  hipLaunchKernelGGL(zero_kernel, dim3(512), dim3(256), 0, stream, (uint32_t*)state0, state_words);
  hipLaunchKernelGGL(transpose_split_kernel, dim3(16,48), dim3(256), 0, stream, Wi0f, sTh, sTl, 1024, 3072);
  hipLaunchKernelGGL((gemm_kernel<0,0>), dim3(8*24), dim3(256), 0, stream,
                     (const void*)W_reg, sTh, sTl, (const float*)nullptr, sWc,
                     (const float*)nullptr, (float*)nullptr, 1024, 3072, 1024);
  hipLaunchKernelGGL(pack_wi_kernel, dim3(4608), dim3(256), 0, stream, sWc, wip, 1024);
  hipLaunchKernelGGL(transpose_split_kernel, dim3(16,48), dim3(256), 0, stream, Wi0b, sTh, sTl, 1024, 3072);
  hipLaunchKernelGGL((gemm_kernel<0,0>), dim3(8*24), dim3(256), 0, stream,
                     (const void*)W_reg, sTh, sTl, (const float*)nullptr, sWc,
                     (const float*)nullptr, (float*)nullptr, 1024, 3072, 1024);
  hipLaunchKernelGGL(pack_wi_kernel, dim3(4608), dim3(256), 0, stream, sWc, wip + (size_t)96*32*1024, 1024);
  hipLaunchKernelGGL(whpack_kernel, dim3(9216), dim3(256), 0, stream, Wh0f, wh_fh, wh_fl);
  hipLaunchKernelGGL(whpack_kernel, dim3(9216), dim3(256), 0, stream, Wh0b, wh_bh, wh_bl);
  hipLaunchKernelGGL(bias_comb_kernel, dim3(12,2), dim3(256), 0, stream, b0f, b0b, Wi0f, Wi0b, b_reg, 1024, bc);
  // ---- BiLSTM layer 0: lat (fp32) -> enc1 (bf16) ----
  hipLaunchKernelGGL((recur_fused<32,1>), dim3(192), dim3(256), 0, stream,
                     (const void*)lat, wip, wh_fh, wh_fl, wh_bh, wh_bl, bc,
                     enc1, nf, hstate, cstate, barr);
  // ---- layer 1 prep ----
  hipLaunchKernelGGL(zero_kernel, dim3(512), dim3(256), 0, stream, (uint32_t*)state0, state_words);
  hipLaunchKernelGGL(pack_wi_kernel, dim3(4608), dim3(256), 0, stream, Wi1f, wip, 1536);
  hipLaunchKernelGGL(pack_wi_kernel, dim3(4608), dim3(256), 0, stream, Wi1b, wip + (size_t)96*32*1536, 1536);
  hipLaunchKernelGGL(whpack_kernel, dim3(9216), dim3(256), 0, stream, Wh1f, wh_fh, wh_fl);
  hipLaunchKernelGGL(whpack_kernel, dim3(9216), dim3(256), 0, stream, Wh1b, wh_bh, wh_bl);
  hipLaunchKernelGGL(bias_comb_kernel, dim3(12,2), dim3(256), 0, stream, b1f, b1b,
                     (const float*)nullptr, (const float*)nullptr, b_reg, 0, bc);
  // ---- BiLSTM layer 1: enc1 (bf16) -> enc2 (bf16) ----
  hipLaunchKernelGGL((recur_fused<48,0>), dim3(192), dim3(256), 0, stream,
                     (const void*)enc1, wip, wh_fh, wh_fl, wh_bh, wh_bl, bc,
                     enc2, nf, hstate, cstate, barr);
  // ---- attention: scores = sum_col tanh(enc2@Wk)*We ----
  hipLaunchKernelGGL(zero_kernel, dim3(128), dim3(256), 0, stream, (uint32_t*)scores, MTOT);
  hipLaunchKernelGGL(transpose_split_kernel, dim3(24,24), dim3(256), 0, stream, W_keys, sTh, sTl, 1536, 1536);
  hipLaunchKernelGGL((gemm_kernel<2,1>), dim3(256*12), dim3(256), 0, stream,
                     (const void*)enc2, sTh, sTl, (const float*)nullptr, (float*)nullptr,
                     W_en, scores, MTOT, 1536, 1536);
  hipLaunchKernelGGL(softmax_kernel, dim3(64), dim3(256), 0, stream, scores, nf, attn);
  hipLaunchKernelGGL(context_kernel, dim3(64), dim3(256), 0, stream, enc2, attn, ctx);
  hipLaunchKernelGGL(post_kernel, dim3(64,6), dim3(256), 0, stream, ctx, W_post, b_post, postb);
  hipLaunchKernelGGL(intents_kernel, dim3(64), dim3(64), 0, stream, postb, W_int, b_int, out);
}

// Round 5
// 23533.414 us; speedup vs baseline: 2.6389x; 1.2872x over previous
//
#include <hip/hip_runtime.h>
#include <cstdint>
#include <cstddef>

// ---------------------------------------------------------------------------
// IntentClassifier on MI355X.
//   dense(1024->1024) folded into layer0 Wi (Wc = W_reg@Wi0)
//   2x BiLSTM (H=768): persistent grid-barrier kernel, x@Wi fused via LDS-
//     resident Wi slice (1-pass bf16), h@Wh with register-pinned split Wh
//     (hi+lo) and bf16 (hi-only) h.
//   R5: h-state loads = batched global_load_dwordx4 (vaddr-pair form, off)
//     sc0 sc1, one vmcnt per step; h stores same form; barrier RMW-free.
// ---------------------------------------------------------------------------

typedef __attribute__((ext_vector_type(8))) short s8v;   // 8 x bf16
typedef __attribute__((ext_vector_type(4))) short s4v;
typedef __attribute__((ext_vector_type(4))) float f4v;
typedef __attribute__((ext_vector_type(4))) int   v4i;

#define MFMA16(a,b,c) __builtin_amdgcn_mfma_f32_16x16x32_bf16((a),(b),(c),0,0,0)

#define NB   64
#define NT   512
#define MTOT (NB*NT)     // 32768 rows

__device__ __forceinline__ ushort f2bf(float x){
  uint32_t u = __float_as_uint(x);
  uint32_t r = (u + 0x7FFFu + ((u >> 16) & 1u)) >> 16;   // RNE
  return (ushort)r;
}
__device__ __forceinline__ float bf2f(ushort h){
  return __uint_as_float(((uint32_t)h) << 16);
}
__device__ __forceinline__ float fsig(float x){
  x = fminf(30.f, fmaxf(-30.f, x));
  return 1.f / (1.f + __expf(-x));
}
__device__ __forceinline__ float ftanh(float x){
  x = fminf(15.f, fmaxf(-15.f, x));
  float e = __expf(2.f * x);
  return (e - 1.f) / (e + 1.f);
}
__device__ __forceinline__ s8v as8(v4i x){ union{v4i a; s8v b;} u; u.a=x; return u.b; }

// ------------------------- weight prep kernels -----------------------------
__global__ void transpose_split_kernel(const float* __restrict__ B,
                                       ushort* __restrict__ Th,
                                       ushort* __restrict__ Tl,
                                       int K, int N){
  __shared__ float tile[64][65];
  int k0 = blockIdx.x * 64, n0 = blockIdx.y * 64;
  for (int i = threadIdx.x; i < 4096; i += 256){
    int r = i >> 6, c = i & 63;
    tile[r][c] = B[(size_t)(k0 + r) * N + (n0 + c)];
  }
  __syncthreads();
  for (int i = threadIdx.x; i < 4096; i += 256){
    int nr = i >> 6, kc = i & 63;
    float x = tile[kc][nr];
    ushort h = f2bf(x);
    ushort lo = f2bf(x - bf2f(h));
    size_t o = (size_t)(n0 + nr) * K + (k0 + kc);
    Th[o] = h; Tl[o] = lo;
  }
}

// Wh (768,3072) fp32 -> fragment-packed bf16 hi/lo: [wgd(96)][nt(2)][kt(24)][lane(64)][j(8)]
__global__ void whpack_kernel(const float* __restrict__ Wh,
                              ushort* __restrict__ Ph, ushort* __restrict__ Pl){
  int idx = blockIdx.x * 256 + threadIdx.x;     // 2,359,296 total
  int j    = idx & 7;
  int lane = (idx >> 3) & 63;
  int kt   = (idx >> 9) % 24;
  int rest = idx / (24 * 512);                  // wgd*2 + nt
  int nt   = rest & 1;
  int wgd  = rest >> 1;
  int c    = lane & 15;
  int gate = nt * 2 + (c >> 3);
  int q    = wgd * 8 + (c & 7);
  int k    = kt * 32 + (lane >> 4) * 8 + j;
  float x = Wh[(size_t)k * 3072 + gate * 768 + q];
  ushort h = f2bf(x);
  Ph[idx] = h;
  Pl[idx] = f2bf(x - bf2f(h));
}

// W (K,3072) fp32 -> packed bf16 [wgd(96)][n(32)][k(K)], col(n)=(n>>3)*768+wgd*8+(n&7)
__global__ void pack_wi_kernel(const float* __restrict__ W,
                               ushort* __restrict__ dst, int K){
  int total = 96 * 32 * K;
  for (int idx = blockIdx.x * 256 + threadIdx.x; idx < total; idx += gridDim.x * 256){
    int k = idx % K;
    int rest = idx / K;            // wgd*32 + n
    int n = rest & 31, wgd = rest >> 5;
    float x = W[(size_t)k * 3072 + (n >> 3) * 768 + wgd * 8 + (n & 7)];
    dst[idx] = f2bf(x);
  }
}

// bc[d][c] = b_d[c] + sum_k breg[k]*W_d[k,c]   (W=nullptr -> plain copy)
__global__ void bias_comb_kernel(const float* __restrict__ bf, const float* __restrict__ bb,
                                 const float* __restrict__ Wf, const float* __restrict__ Wb,
                                 const float* __restrict__ breg, int Kb,
                                 float* __restrict__ bc){
  int c = blockIdx.x * 256 + threadIdx.x;   // < 3072
  int d = blockIdx.y;
  const float* b = d ? bb : bf;
  const float* W = d ? Wb : Wf;
  float acc = b[c];
  if (W){
    for (int k = 0; k < Kb; k++) acc += breg[k] * W[(size_t)k * 3072 + c];
  }
  bc[d * 3072 + c] = acc;
}

__global__ void zero_kernel(uint32_t* __restrict__ p, int n){
  for (int i = blockIdx.x * 256 + threadIdx.x; i < n; i += gridDim.x * 256)
    p[i] = 0u;
}

// ------------------------- split-bf16 GEMM ---------------------------------
// MODE 0: C = A@B + bias (fp32 out).   MODE 2: scores[row] += sum_col tanh(C)*We[col]
// ABF 0: A fp32 (split in-kernel, 3-pass).  ABF 1: A bf16 (2-pass)
template<int MODE, int ABF>
__global__ __launch_bounds__(256, 2) void gemm_kernel(
    const void* __restrict__ Araw, const ushort* __restrict__ Bh,
    const ushort* __restrict__ Bl, const float* __restrict__ bias,
    float* __restrict__ outF,
    const float* __restrict__ We, float* __restrict__ scores,
    int M, int N, int K)
{
  __shared__ short lA_h[128*40], lA_l[128*40], lB_h[128*40], lB_l[128*40];
  int tid = threadIdx.x, l = tid & 63, w = tid >> 6;
  int wr = w >> 1, wc = w & 1;
  int nbM = M >> 7;
  int mblk = blockIdx.x % nbM, nblk = blockIdx.x / nbM;
  f4v acc[4][4];
  for (int i=0;i<4;i++) for (int j=0;j<4;j++) acc[i][j] = (f4v){0.f,0.f,0.f,0.f};
  int nk = K >> 5;
  const ushort* Bhb = Bh + (size_t)nblk*128*K;
  const ushort* Blb = Bl + (size_t)nblk*128*K;
  int mrow = l & 15, koff = (l >> 4) * 8;
  for (int kt = 0; kt < nk; kt++){
    if (ABF == 0){   // fp32 A -> split hi/lo
      const float* Ab = (const float*)Araw + (size_t)mblk*128*K;
      int c4 = (l & 7) * 4;
      #pragma unroll
      for (int i=0;i<4;i++){
        int r = (w*4 + i)*8 + (l >> 3);
        const float* p = Ab + (size_t)r*K + kt*32 + c4;
        float4 v = *(const float4*)p;
        float xs[4] = {v.x, v.y, v.z, v.w};
        s4v hv, lv;
        #pragma unroll
        for (int j=0;j<4;j++){
          ushort hh = f2bf(xs[j]);
          hv[j] = (short)hh;
          lv[j] = (short)f2bf(xs[j] - bf2f(hh));
        }
        *(s4v*)&lA_h[r*40 + c4] = hv;
        *(s4v*)&lA_l[r*40 + c4] = lv;
      }
    } else {         // bf16 A
      const ushort* Ab = (const ushort*)Araw + (size_t)mblk*128*K;
      int k8 = (l & 3) * 8;
      #pragma unroll
      for (int i=0;i<2;i++){
        int r = (w*2 + i)*16 + (l >> 2);
        *(s8v*)&lA_h[r*40 + k8] = *(const s8v*)(Ab + (size_t)r*K + kt*32 + k8);
      }
    }
    {
      int k8 = (l & 3) * 8;
      #pragma unroll
      for (int i=0;i<2;i++){
        int r = (w*2 + i)*16 + (l >> 2);
        size_t o = (size_t)r*K + kt*32 + k8;
        *(s8v*)&lB_h[r*40 + k8] = *(const s8v*)(Bhb + o);
        *(s8v*)&lB_l[r*40 + k8] = *(const s8v*)(Blb + o);
      }
    }
    __syncthreads();
    s8v ah[4], al[4], bh[4], bl[4];
    #pragma unroll
    for (int mt=0;mt<4;mt++){
      int base = (wr*64 + mt*16 + mrow)*40 + koff;
      ah[mt] = *(s8v*)&lA_h[base];
      if (ABF == 0) al[mt] = *(s8v*)&lA_l[base];
    }
    #pragma unroll
    for (int nt=0;nt<4;nt++){
      int base = (wc*64 + nt*16 + mrow)*40 + koff;
      bh[nt] = *(s8v*)&lB_h[base];
      bl[nt] = *(s8v*)&lB_l[base];
    }
    #pragma unroll
    for (int mt=0;mt<4;mt++)
      #pragma unroll
      for (int nt=0;nt<4;nt++){
        acc[mt][nt] = MFMA16(ah[mt], bh[nt], acc[mt][nt]);
        acc[mt][nt] = MFMA16(ah[mt], bl[nt], acc[mt][nt]);
        if (ABF == 0) acc[mt][nt] = MFMA16(al[mt], bh[nt], acc[mt][nt]);
      }
    __syncthreads();
  }
  // epilogue. C/D layout: col = lane&15, row = (lane>>4)*4 + r
  if (MODE == 2){
    float pre[4][4];
    #pragma unroll
    for (int mt=0;mt<4;mt++) for (int r=0;r<4;r++) pre[mt][r] = 0.f;
    #pragma unroll
    for (int nt=0;nt<4;nt++){
      int colg = nblk*128 + wc*64 + nt*16 + (l & 15);
      float we = We[colg];
      #pragma unroll
      for (int mt=0;mt<4;mt++)
        #pragma unroll
        for (int r=0;r<4;r++)
          pre[mt][r] += ftanh(acc[mt][nt][r]) * we;
    }
    #pragma unroll
    for (int mt=0;mt<4;mt++)
      #pragma unroll
      for (int r=0;r<4;r++){
        float v = pre[mt][r];
        v += __shfl_xor(v, 1); v += __shfl_xor(v, 2);
        v += __shfl_xor(v, 4); v += __shfl_xor(v, 8);
        if ((l & 15) == 0){
          int rowg = mblk*128 + wr*64 + mt*16 + (l>>4)*4 + r;
          atomicAdd(scores + rowg, v);
        }
      }
  } else {
    #pragma unroll
    for (int mt=0;mt<4;mt++)
      #pragma unroll
      for (int nt=0;nt<4;nt++){
        int rowg0 = mblk*128 + wr*64 + mt*16 + (l>>4)*4;
        int colg  = nblk*128 + wc*64 + nt*16 + (l & 15);
        float bv = bias ? bias[colg] : 0.f;
        #pragma unroll
        for (int r=0;r<4;r++){
          float v = acc[mt][nt][r] + bv;
          outF[(size_t)(rowg0 + r)*N + colg] = v;
        }
      }
  }
}

// ------------------------- fused persistent BiLSTM -------------------------
// grid = 192 x 256. dir = bx&1, wgd = bx>>1 owns 8 h-cols (32 z-cols).
// h hi-only (bf16); Wh split hi/lo in registers (2-pass h@Wh).
// h loads: 24 batched global_load_dwordx4 (vaddr form) sc0 sc1, one vmcnt.
// barrier: slot stores + wg0 poll + gen flag; no atomic RMWs.
template<int NKT, int XF32>
__global__ __launch_bounds__(256, 1) void recur_fused(
    const void* __restrict__ xsrc, const ushort* __restrict__ wip,
    const ushort* __restrict__ whfh, const ushort* __restrict__ whfl,
    const ushort* __restrict__ whbh, const ushort* __restrict__ whbl,
    const float* __restrict__ bias2, ushort* __restrict__ enc,
    const int* __restrict__ nf, ushort* __restrict__ hstate,
    float* __restrict__ cstate, int* __restrict__ barr)
{
  constexpr int K  = NKT * 32;
  constexpr int KP = K + 8;
  constexpr int KPW = NKT / 4;
  __shared__ ushort wilds[32 * KP];
  __shared__ float zlds[9216];        // [w][mt][nt][col16][row pad18]
  __shared__ float bcs[32];
  __shared__ int nfs[64];
  __shared__ int lmaxs[4];
  const int tid = threadIdx.x, l = tid & 63, w = tid >> 6;
  const int dir = blockIdx.x & 1, wgd = blockIdx.x >> 1, wq0 = wgd * 8;

  { // stage this wg's Wi slice into LDS
    const ushort* wsrc = wip + ((size_t)(dir*96 + wgd)) * 32 * K;
    for (int idx = tid; idx < 32 * (K/8); idx += 256){
      int row = idx / (K/8);
      int c8  = (idx - row * (K/8)) * 8;
      *(s8v*)&wilds[row*KP + c8] = *(const s8v*)(wsrc + (size_t)row*K + c8);
    }
  }
  if (tid < 64) nfs[tid] = nf[tid];
  if (tid < 32) bcs[tid] = bias2[dir*3072 + (tid>>3)*768 + wq0 + (tid&7)];
  __syncthreads();
  if (tid < 4){
    int m = 0;
    for (int i=0;i<16;i++) m = max(m, nfs[tid*16 + i]);
    lmaxs[tid] = m;
  }
  __syncthreads();
  int lm[4], Lbl[4];
  #pragma unroll
  for (int mt=0;mt<4;mt++){ lm[mt] = lmaxs[mt]; Lbl[mt] = nfs[mt*16 + (l&15)]; }
  // gate cells: thread owns 2 ADJACENT cols (q0=2*qp, q0+1) of batch gb
  const int gb = tid >> 2, qp = tid & 3, q0 = qp*2;
  const int gL = nfs[gb];
  const int ghidx = gb*768 + wq0 + q0;          // dword-aligned (q0 even)
  float* cst = cstate + dir * 49152;

  const ushort* wph = dir ? whbh : whfh;
  const ushort* wpl = dir ? whbl : whfl;
  s8v whh[2][6], whl[2][6];
  #pragma unroll
  for (int nt=0;nt<2;nt++)
    for (int i=0;i<6;i++){
      size_t o = ((size_t)((wgd*2 + nt)*24 + (w*6 + i)) * 64 + l) * 8;
      whh[nt][i] = *(const s8v*)(wph + o);
      whl[nt][i] = *(const s8v*)(wpl + o);
    }

  // h fragment byte offsets (step-invariant): frag(i,mt) at hoff[mt] + i*64
  uint32_t hoff[4];
  #pragma unroll
  for (int mt=0;mt<4;mt++)
    hoff[mt] = (uint32_t)(((mt*16 + (l & 15))*768 + w*192 + ((l>>4)*8)) * 2);
  // hstate hi-only: [dir(2)][phase(2)][49152]
  uint64_t hb0 = (uint64_t)(uintptr_t)(hstate + (size_t)(dir*2 + 0)*49152);
  uint64_t hb1 = (uint64_t)(uintptr_t)(hstate + (size_t)(dir*2 + 1)*49152);

  f4v aX[4][2];
  auto xpart = [&](int t){
    #pragma unroll
    for (int mt=0;mt<4;mt++){ aX[mt][0]=(f4v){0.f,0.f,0.f,0.f}; aX[mt][1]=(f4v){0.f,0.f,0.f,0.f}; }
    #pragma unroll
    for (int i=0;i<KPW;i++){
      int kt = w*KPW + i;
      int kc = kt*32 + (l>>4)*8;
      s8v bf0 = *(const s8v*)&wilds[(l & 15)*KP + kc];
      s8v bf1 = *(const s8v*)&wilds[(16 + (l & 15))*KP + kc];
      #pragma unroll
      for (int mt=0;mt<4;mt++){
        if (t >= lm[mt]) continue;
        int bb = mt*16 + (l & 15);
        int r = t;
        if (dir && t < Lbl[mt]) r = Lbl[mt] - 1 - t;
        size_t off = ((size_t)bb*512 + r)*K + kc;
        s8v a;
        if constexpr (XF32){
          const float* xf = (const float*)xsrc;
          float4 u0 = *(const float4*)(xf + off);
          float4 u1 = *(const float4*)(xf + off + 4);
          a[0]=(short)f2bf(u0.x); a[1]=(short)f2bf(u0.y);
          a[2]=(short)f2bf(u0.z); a[3]=(short)f2bf(u0.w);
          a[4]=(short)f2bf(u1.x); a[5]=(short)f2bf(u1.y);
          a[6]=(short)f2bf(u1.z); a[7]=(short)f2bf(u1.w);
        } else {
          a = *(const s8v*)((const ushort*)xsrc + off);
        }
        aX[mt][0] = MFMA16(a, bf0, aX[mt][0]);
        aX[mt][1] = MFMA16(a, bf1, aX[mt][1]);
      }
    }
  };
  xpart(0);

  const int wgid = blockIdx.x;
  uint32_t lasth = 0;

  for (int t = 0; t < 512; t++){
    if (t > 0 && wgid != 0 && tid == 0){
      while (__hip_atomic_load(barr + 256, __ATOMIC_RELAXED, __HIP_MEMORY_SCOPE_AGENT) < t)
        __builtin_amdgcn_s_sleep(2);
    }
    __syncthreads();
    const int p = t & 1;
    const uint64_t rb = p ? hb1 : hb0;
    const uint64_t wb = p ? hb0 : hb1;

    // ---- batched coherent h-loads: 24 x 16B via v[addr] form, one waitcnt ----
    v4i F[4][6];
    #pragma unroll
    for (int mt=0; mt<4; mt++){
      uint64_t amt = rb + hoff[mt];
      asm volatile(
        "global_load_dwordx4 %0, %6, off sc0 sc1\n\t"
        "global_load_dwordx4 %1, %6, off offset:64 sc0 sc1\n\t"
        "global_load_dwordx4 %2, %6, off offset:128 sc0 sc1\n\t"
        "global_load_dwordx4 %3, %6, off offset:192 sc0 sc1\n\t"
        "global_load_dwordx4 %4, %6, off offset:256 sc0 sc1\n\t"
        "global_load_dwordx4 %5, %6, off offset:320 sc0 sc1"
        : "=&v"(F[mt][0]),"=&v"(F[mt][1]),"=&v"(F[mt][2]),
          "=&v"(F[mt][3]),"=&v"(F[mt][4]),"=&v"(F[mt][5])
        : "v"(amt)
        : "memory");
    }
    asm volatile("s_waitcnt vmcnt(0)"
      : "+v"(F[0][0]),"+v"(F[0][1]),"+v"(F[0][2]),"+v"(F[0][3]),"+v"(F[0][4]),"+v"(F[0][5]),
        "+v"(F[1][0]),"+v"(F[1][1]),"+v"(F[1][2]),"+v"(F[1][3]),"+v"(F[1][4]),"+v"(F[1][5]),
        "+v"(F[2][0]),"+v"(F[2][1]),"+v"(F[2][2]),"+v"(F[2][3]),"+v"(F[2][4]),"+v"(F[2][5]),
        "+v"(F[3][0]),"+v"(F[3][1]),"+v"(F[3][2]),"+v"(F[3][3]),"+v"(F[3][4]),"+v"(F[3][5])
      :
      : "memory");

    f4v acc[4][2];
    #pragma unroll
    for (int mt=0;mt<4;mt++){ acc[mt][0] = aX[mt][0]; acc[mt][1] = aX[mt][1]; }
    #pragma unroll
    for (int i=0;i<6;i++){
      #pragma unroll
      for (int mt=0;mt<4;mt++){
        s8v ahh = as8(F[mt][i]);
        acc[mt][0] = MFMA16(ahh, whh[0][i], acc[mt][0]);
        acc[mt][0] = MFMA16(ahh, whl[0][i], acc[mt][0]);
        acc[mt][1] = MFMA16(ahh, whh[1][i], acc[mt][1]);
        acc[mt][1] = MFMA16(ahh, whl[1][i], acc[mt][1]);
      }
    }
    #pragma unroll
    for (int mt=0;mt<4;mt++)
      #pragma unroll
      for (int nt=0;nt<2;nt++){
        int base = (((w*4 + mt)*2 + nt)*16 + (l & 15))*18 + (l>>4)*4;
        zlds[base+0] = acc[mt][nt][0];
        zlds[base+1] = acc[mt][nt][1];
        zlds[base+2] = acc[mt][nt][2];
        zlds[base+3] = acc[mt][nt][3];
      }
    __syncthreads();
    { // gates: 2 adjacent cols per thread
      if (t < gL){
        int mt = gb >> 4, row = gb & 15;
        float nhv[2];
        #pragma unroll
        for (int e=0;e<2;e++){
          int q = q0 + e;
          float zg4[4];
          #pragma unroll
          for (int g=0; g<4; g++){
            int nt = g >> 1, c = (g & 1)*8 + q;
            int zb = ((mt*2 + nt)*16 + c)*18 + row;
            zg4[g] = zlds[zb] + zlds[zb+2304] + zlds[zb+4608] + zlds[zb+6912] + bcs[g*8 + q];
          }
          float co = cst[ghidx + e];
          float nc = fsig(zg4[1])*co + fsig(zg4[0])*ftanh(zg4[2]);
          float nh = fsig(zg4[3])*ftanh(nc);
          cst[ghidx + e] = nc;
          nhv[e] = nh;
        }
        ushort h0h = f2bf(nhv[0]), h1h = f2bf(nhv[1]);
        uint32_t pk = (uint32_t)h0h | ((uint32_t)h1h << 16);
        lasth = pk;
        uint64_t sa = wb + (uint32_t)(ghidx * 2);
        asm volatile("global_store_dword %0, %1, off sc0 sc1"
                     :: "v"(sa), "v"(pk) : "memory");
        int r = dir ? (gL - 1 - t) : t;
        *(uint32_t*)&enc[((size_t)gb*512 + r)*1536 + dir*768 + wq0 + q0] = pk;
      } else if (t == gL){
        uint64_t sa = wb + (uint32_t)(ghidx * 2);
        asm volatile("global_store_dword %0, %1, off sc0 sc1"
                     :: "v"(sa), "v"(lasth) : "memory");
      }
    }
    asm volatile("s_waitcnt vmcnt(0)" ::: "memory");  // h stores ack'd at IC
    __syncthreads();
    if (t < 511){
      if (tid == 0)   // arrive: plain coherent store to private slot
        __hip_atomic_store(barr + wgid, t + 1, __ATOMIC_RELAXED, __HIP_MEMORY_SCOPE_AGENT);
      xpart(t + 1);   // prefetch next x@Wi while others arrive
      if (wgid == 0 && w == 0){   // master: poll 192 slots, release gen
        for (;;){
          int v0 = __hip_atomic_load(barr + l,       __ATOMIC_RELAXED, __HIP_MEMORY_SCOPE_AGENT);
          int v1 = __hip_atomic_load(barr + 64 + l,  __ATOMIC_RELAXED, __HIP_MEMORY_SCOPE_AGENT);
          int v2 = __hip_atomic_load(barr + 128 + l, __ATOMIC_RELAXED, __HIP_MEMORY_SCOPE_AGENT);
          int mn = min(v0, min(v1, v2));
          if (__all(mn >= t + 1)) break;
          __builtin_amdgcn_s_sleep(1);
        }
        if (l == 0)
          __hip_atomic_store(barr + 256, t + 1, __ATOMIC_RELAXED, __HIP_MEMORY_SCOPE_AGENT);
      }
    }
  }
}

// ------------------------- attention tail ----------------------------------
__global__ void softmax_kernel(const float* __restrict__ scores,
                               const int* __restrict__ nf,
                               float* __restrict__ attn){
  __shared__ float red[4], red2[4];
  int b = blockIdx.x, tid = threadIdx.x;
  int L = nf[b];
  float v0 = (tid       < L) ? scores[b*512 + tid]       : -1e30f;
  float v1 = (tid + 256 < L) ? scores[b*512 + tid + 256] : -1e30f;
  float mx = fmaxf(v0, v1);
  for (int m=1; m<64; m<<=1) mx = fmaxf(mx, __shfl_xor(mx, m));
  if ((tid & 63) == 0) red[tid >> 6] = mx;
  __syncthreads();
  mx = fmaxf(fmaxf(red[0], red[1]), fmaxf(red[2], red[3]));
  float e0 = (tid       < L) ? __expf(v0 - mx) : 0.f;
  float e1 = (tid + 256 < L) ? __expf(v1 - mx) : 0.f;
  float s = e0 + e1;
  for (int m=1; m<64; m<<=1) s += __shfl_xor(s, m);
  if ((tid & 63) == 0) red2[tid >> 6] = s;
  __syncthreads();
  s = red2[0] + red2[1] + red2[2] + red2[3];
  float inv = 1.f / s;
  attn[b*512 + tid]       = e0 * inv;
  attn[b*512 + tid + 256] = e1 * inv;
}

__global__ void context_kernel(const ushort* __restrict__ enc,
                               const float* __restrict__ attn,
                               float* __restrict__ ctx){
  int b = blockIdx.x, tid = threadIdx.x;
  float a6[6] = {0.f,0.f,0.f,0.f,0.f,0.f};
  for (int t=0; t<512; t++){
    float a = attn[b*512 + t];
    if (a != 0.f){
      const ushort* e = enc + ((size_t)b*512 + t)*1536;
      #pragma unroll
      for (int i=0;i<6;i++) a6[i] += a * bf2f(e[tid + i*256]);
    }
  }
  #pragma unroll
  for (int i=0;i<6;i++) ctx[b*1536 + tid + i*256] = a6[i];
}

__global__ void post_kernel(const float* __restrict__ ctx,
                            const float* __restrict__ Wp,
                            const float* __restrict__ bp,
                            float* __restrict__ post){
  int b = blockIdx.x;
  int j = blockIdx.y*256 + threadIdx.x;
  float acc = bp[j];
  const float* c = ctx + b*1536;
  for (int k=0;k<1536;k++) acc += c[k] * Wp[(size_t)k*1536 + j];
  post[b*1536 + j] = acc;
}

__global__ void intents_kernel(const float* __restrict__ post,
                               const float* __restrict__ Wi,
                               const float* __restrict__ bi,
                               float* __restrict__ out){
  int b = blockIdx.x, j = threadIdx.x;
  if (j < 60){
    float acc = bi[j];
    const float* p = post + b*1536;
    for (int k=0;k<1536;k++) acc += p[k] * Wi[k*60 + j];
    out[b*60 + j] = acc;
  }
}

// ------------------------- host side ---------------------------------------
extern "C" void kernel_launch(void* const* d_in, const int* in_sizes, int n_in,
                              void* d_out, int out_size, void* d_ws, size_t ws_size,
                              hipStream_t stream) {
  const float* lat    = (const float*)d_in[0];
  const int*   nf     = (const int*)  d_in[1];
  const float* W_reg  = (const float*)d_in[3];
  const float* b_reg  = (const float*)d_in[4];
  const float* Wi0f   = (const float*)d_in[5];
  const float* Wh0f   = (const float*)d_in[6];
  const float* b0f    = (const float*)d_in[7];
  const float* Wi0b   = (const float*)d_in[8];
  const float* Wh0b   = (const float*)d_in[9];
  const float* b0b    = (const float*)d_in[10];
  const float* Wi1f   = (const float*)d_in[11];
  const float* Wh1f   = (const float*)d_in[12];
  const float* b1f    = (const float*)d_in[13];
  const float* Wi1b   = (const float*)d_in[14];
  const float* Wh1b   = (const float*)d_in[15];
  const float* b1b    = (const float*)d_in[16];
  const float* W_keys = (const float*)d_in[17];
  const float* W_en   = (const float*)d_in[18];
  const float* W_post = (const float*)d_in[19];
  const float* b_post = (const float*)d_in[20];
  const float* W_int  = (const float*)d_in[21];
  const float* b_int  = (const float*)d_in[22];
  float* out = (float*)d_out;

  char* wsp = (char*)d_ws;
  auto alloc = [&](size_t n) -> char* {
    char* p = wsp; wsp += (n + 255) & ~(size_t)255; return p;
  };
  ushort* enc1 = (ushort*)alloc((size_t)MTOT*1536*2);
  ushort* enc2 = (ushort*)alloc((size_t)MTOT*1536*2);
  ushort* wip  = (ushort*)alloc((size_t)2*96*32*1536*2);
  ushort* wh_fh = (ushort*)alloc((size_t)2359296*2);
  ushort* wh_fl = (ushort*)alloc((size_t)2359296*2);
  ushort* wh_bh = (ushort*)alloc((size_t)2359296*2);
  ushort* wh_bl = (ushort*)alloc((size_t)2359296*2);
  ushort* sTh  = (ushort*)alloc((size_t)3072*1024*2);
  ushort* sTl  = (ushort*)alloc((size_t)3072*1024*2);
  float*  sWc  = (float*) alloc((size_t)1024*3072*4);
  float*  bc   = (float*) alloc((size_t)2*3072*4);
  char* state0 = wsp;
  ushort* hstate = (ushort*)alloc((size_t)4*49152*2);   // hi-only: dir x phase
  float*  cstate = (float*) alloc((size_t)2*49152*4);
  int*    barr   = (int*)   alloc(4096);
  size_t state_bytes = (size_t)((char*)wsp - state0);
  float* scores = (float*)alloc((size_t)MTOT*4);
  float* attn   = (float*)alloc((size_t)MTOT*4);
  float* ctx    = (float*)alloc((size_t)NB*1536*4);
  float* postb  = (float*)alloc((size_t)NB*1536*4);
  (void)in_sizes; (void)n_in; (void)out_size; (void)ws_size;

  int state_words = (int)(state_bytes / 4);

  // ---- layer 0 prep: Wc = W_reg @ Wi0{f,b}, pack; Wh0 packs; bias comb ----
  hipLaunchKernelGGL(zero_kernel, dim3(512), dim3(256), 0, stream, (uint32_t*)state0, state_words);
  hipLaunchKernelGGL(transpose_split_kernel, dim3(16,48), dim3(256), 0, stream, Wi0f, sTh, sTl, 1024, 3072);
  hipLaunchKernelGGL((gemm_kernel<0,0>), dim3(8*24), dim3(256), 0, stream,
                     (const void*)W_reg, sTh, sTl, (const float*)nullptr, sWc,
                     (const float*)nullptr, (float*)nullptr, 1024, 3072, 1024);
  hipLaunchKernelGGL(pack_wi_kernel, dim3(4608), dim3(256), 0, stream, sWc, wip, 1024);
  hipLaunchKernelGGL(transpose_split_kernel, dim3(16,48), dim3(256), 0, stream, Wi0b, sTh, sTl, 1024, 3072);
  hipLaunchKernelGGL((gemm_kernel<0,0>), dim3(8*24), dim3(256), 0, stream,
                     (const void*)W_reg, sTh, sTl, (const float*)nullptr, sWc,
                     (const float*)nullptr, (float*)nullptr, 1024, 3072, 1024);
  hipLaunchKernelGGL(pack_wi_kernel, dim3(4608), dim3(256), 0, stream, sWc, wip + (size_t)96*32*1024, 1024);
  hipLaunchKernelGGL(whpack_kernel, dim3(9216), dim3(256), 0, stream, Wh0f, wh_fh, wh_fl);
  hipLaunchKernelGGL(whpack_kernel, dim3(9216), dim3(256), 0, stream, Wh0b, wh_bh, wh_bl);
  hipLaunchKernelGGL(bias_comb_kernel, dim3(12,2), dim3(256), 0, stream, b0f, b0b, Wi0f, Wi0b, b_reg, 1024, bc);
  // ---- BiLSTM layer 0: lat (fp32) -> enc1 (bf16) ----
  hipLaunchKernelGGL((recur_fused<32,1>), dim3(192), dim3(256), 0, stream,
                     (const void*)lat, wip, wh_fh, wh_fl, wh_bh, wh_bl, bc,
                     enc1, nf, hstate, cstate, barr);
  // ---- layer 1 prep ----
  hipLaunchKernelGGL(zero_kernel, dim3(512), dim3(256), 0, stream, (uint32_t*)state0, state_words);
  hipLaunchKernelGGL(pack_wi_kernel, dim3(4608), dim3(256), 0, stream, Wi1f, wip, 1536);
  hipLaunchKernelGGL(pack_wi_kernel, dim3(4608), dim3(256), 0, stream, Wi1b, wip + (size_t)96*32*1536, 1536);
  hipLaunchKernelGGL(whpack_kernel, dim3(9216), dim3(256), 0, stream, Wh1f, wh_fh, wh_fl);
  hipLaunchKernelGGL(whpack_kernel, dim3(9216), dim3(256), 0, stream, Wh1b, wh_bh, wh_bl);
  hipLaunchKernelGGL(bias_comb_kernel, dim3(12,2), dim3(256), 0, stream, b1f, b1b,
                     (const float*)nullptr, (const float*)nullptr, b_reg, 0, bc);
  // ---- BiLSTM layer 1: enc1 (bf16) -> enc2 (bf16) ----
  hipLaunchKernelGGL((recur_fused<48,0>), dim3(192), dim3(256), 0, stream,
                     (const void*)enc1, wip, wh_fh, wh_fl, wh_bh, wh_bl, bc,
                     enc2, nf, hstate, cstate, barr);
  // ---- attention: scores = sum_col tanh(enc2@Wk)*We ----
  hipLaunchKernelGGL(zero_kernel, dim3(128), dim3(256), 0, stream, (uint32_t*)scores, MTOT);
  hipLaunchKernelGGL(transpose_split_kernel, dim3(24,24), dim3(256), 0, stream, W_keys, sTh, sTl, 1536, 1536);
  hipLaunchKernelGGL((gemm_kernel<2,1>), dim3(256*12), dim3(256), 0, stream,
                     (const void*)enc2, sTh, sTl, (const float*)nullptr, (float*)nullptr,
                     W_en, scores, MTOT, 1536, 1536);
  hipLaunchKernelGGL(softmax_kernel, dim3(64), dim3(256), 0, stream, scores, nf, attn);
  hipLaunchKernelGGL(context_kernel, dim3(64), dim3(256), 0, stream, enc2, attn, ctx);
  hipLaunchKernelGGL(post_kernel, dim3(64,6), dim3(256), 0, stream, ctx, W_post, b_post, postb);
  hipLaunchKernelGGL(intents_kernel, dim3(64), dim3(64), 0, stream, postb, W_int, b_int, out);
}